// Round 1
// baseline (149.340 us; speedup 1.0000x reference)
//
#include <hip/hip_runtime.h>
#include <math.h>

#define P_NODES 21
#define KNEG    5
#define DDIM    128
#define BATCH   1024
#define N_PAIRS 185   // sum of window sizes for P=21, k=5

struct Pairs { unsigned char pi[N_PAIRS]; unsigned char pj[N_PAIRS]; };

constexpr Pairs make_pairs() {
    Pairs p{};
    int n = 0;
    for (int i = 0; i < P_NODES; ++i) {
        int jlo = (i - KNEG > 0) ? i - KNEG : 0;
        int jhi = (i + KNEG < P_NODES) ? i + KNEG : P_NODES;
        for (int j = jlo; j < jhi; ++j) { p.pi[n] = (unsigned char)i; p.pj[n] = (unsigned char)j; ++n; }
    }
    return p;
}

__constant__ Pairs PAIRS = make_pairs();

__device__ __forceinline__ float log_sigmoid(float x) {
    // stable: min(x,0) - log1p(exp(-|x|))
    float a = fabsf(x);
    return fminf(x, 0.f) - log1pf(__expf(-a));
}

__global__ __launch_bounds__(512, 2) void mp2v_loss_kernel(
    const float* __restrict__ emb,
    const int*   __restrict__ path,
    const int*   __restrict__ neg,
    float*       __restrict__ out)
{
    __shared__ float rows[P_NODES][DDIM];          // 10.5 KB: the 21 path rows for this b
    __shared__ int   nidx[N_PAIRS * KNEG];         // 3.7 KB: neg indices for this b
    __shared__ float wsum[8];                      // per-wave partials

    const int b   = blockIdx.x;
    const int tid = threadIdx.x;
    const int nth = blockDim.x;

    // ---- stage the 21 path embedding rows into LDS (coalesced 512B rows) ----
    const int* pb = path + b * P_NODES;
    for (int e = tid; e < P_NODES * DDIM; e += nth) {
        int r = e >> 7;        // / 128
        int c = e & 127;
        rows[r][c] = emb[pb[r] * DDIM + c];
    }
    // ---- stage the 925 neg indices for this b ----
    for (int q = tid; q < N_PAIRS * KNEG; q += nth) {
        int p = q / KNEG;
        int k = q - p * KNEG;
        nidx[q] = neg[(p * BATCH + b) * KNEG + k];
    }
    __syncthreads();

    // ---- half-wave per dot task: 32 lanes x float4 = 512 B = one emb row ----
    const int hw   = tid >> 5;       // half-wave id within block
    const int lane = tid & 31;
    const int nhw  = nth >> 5;

    float acc = 0.f;

    const int NTASK = N_PAIRS * (KNEG + 1);  // 185 pos + 925 neg = 1110
    for (int q = hw; q < NTASK; q += nhw) {
        const float4* src;
        int   ci;
        float sgn;
        if (q < N_PAIRS) {
            ci  = PAIRS.pi[q];
            src = (const float4*)&rows[PAIRS.pj[q]][0];
            sgn = 1.f;
        } else {
            int t = q - N_PAIRS;
            int p = t / KNEG;
            ci  = PAIRS.pi[p];
            src = (const float4*)(emb + nidx[t] * DDIM);
            sgn = -1.f;
        }
        float4 v = src[lane];
        float4 c = ((const float4*)&rows[ci][0])[lane];
        float part = v.x * c.x + v.y * c.y + v.z * c.z + v.w * c.w;
        // butterfly reduce within the 32-lane half (xor masks < 32 stay in-half)
        part += __shfl_xor(part, 16);
        part += __shfl_xor(part, 8);
        part += __shfl_xor(part, 4);
        part += __shfl_xor(part, 2);
        part += __shfl_xor(part, 1);
        if (lane == 0) acc += log_sigmoid(part * sgn);
    }

    // ---- block reduction (full 64-lane wave reduce, then LDS across waves) ----
    acc += __shfl_xor(acc, 32);
    acc += __shfl_xor(acc, 16);
    acc += __shfl_xor(acc, 8);
    acc += __shfl_xor(acc, 4);
    acc += __shfl_xor(acc, 2);
    acc += __shfl_xor(acc, 1);
    if ((tid & 63) == 0) wsum[tid >> 6] = acc;
    __syncthreads();
    if (tid == 0) {
        float s = 0.f;
        int nw = nth >> 6;
        for (int w = 0; w < nw; ++w) s += wsum[w];
        atomicAdd(out, s * (-1.f / (float)BATCH));
    }
}

extern "C" void kernel_launch(void* const* d_in, const int* in_sizes, int n_in,
                              void* d_out, int out_size, void* d_ws, size_t ws_size,
                              hipStream_t stream) {
    const float* emb  = (const float*)d_in[0];
    const int*   path = (const int*)d_in[1];
    const int*   neg  = (const int*)d_in[2];
    float*       out  = (float*)d_out;

    // d_out is poisoned once before timing and never re-poisoned: zero it each call.
    hipMemsetAsync(out, 0, sizeof(float), stream);

    mp2v_loss_kernel<<<BATCH, 512, 0, stream>>>(emb, path, neg, out);
}